// Round 1
// baseline (165.391 us; speedup 1.0000x reference)
//
#include <hip/hip_runtime.h>
#include <math.h>

#define T_LEN 256
#define HID 10

typedef float v2f __attribute__((ext_vector_type(2)));

__device__ __forceinline__ v2f mk2(float a, float b) { v2f r; r.x = a; r.y = b; return r; }
__device__ __forceinline__ v2f splat2(float a) { return mk2(a, a); }

// setup-only accurate softplus
__device__ __forceinline__ float softplus_f(float x) {
    return fmaxf(x, 0.0f) + log1pf(expf(-fabsf(x)));
}
__device__ __forceinline__ float samp(const float* mu, const float* rho,
                                      const float* eps, int i) {
    return mu[i] + softplus_f(rho[i]) * eps[i];
}

// sigmoid = rcp(1 + 2^(-log2e*x))
__device__ __forceinline__ float fast_sigmoid(float x) {
    float e = __builtin_amdgcn_exp2f(-1.442695040888963f * x);
    return __builtin_amdgcn_rcpf(1.0f + e);
}
// tanh(x) = 1 - 2/(2^(2*log2e*x)+1)
__device__ __forceinline__ float fast_tanh(float x) {
    float e = __builtin_amdgcn_exp2f(2.885390081777927f * x);
    return fmaf(-2.0f, __builtin_amdgcn_rcpf(e + 1.0f), 1.0f);
}

struct Wreg {
    v2f whh01[HID], whh23[HID];   // recurrent cols {i,f} / {g,o} for this lane's unit
    v2f wih01, wih23, b01, b23;
};

// one LSTM step for one element; h comes in as 3 float4s (h[0..9] + 2 pad)
__device__ __forceinline__ float lstm_step(const Wreg& w, float xt,
                                           float4 h0, float4 h1, float4 h2,
                                           float& c)
{
    v2f x2 = splat2(xt);
    // even-j chain (seeded with x/bias) and odd-j chain, combined once
    v2f e01 = __builtin_elementwise_fma(x2, w.wih01, w.b01);
    v2f e23 = __builtin_elementwise_fma(x2, w.wih23, w.b23);
    v2f o01 = w.whh01[1] * splat2(h0.y);
    v2f o23 = w.whh23[1] * splat2(h0.y);
    e01 = __builtin_elementwise_fma(splat2(h0.x), w.whh01[0], e01);
    e23 = __builtin_elementwise_fma(splat2(h0.x), w.whh23[0], e23);
    o01 = __builtin_elementwise_fma(splat2(h0.w), w.whh01[3], o01);
    o23 = __builtin_elementwise_fma(splat2(h0.w), w.whh23[3], o23);
    e01 = __builtin_elementwise_fma(splat2(h0.z), w.whh01[2], e01);
    e23 = __builtin_elementwise_fma(splat2(h0.z), w.whh23[2], e23);
    o01 = __builtin_elementwise_fma(splat2(h1.y), w.whh01[5], o01);
    o23 = __builtin_elementwise_fma(splat2(h1.y), w.whh23[5], o23);
    e01 = __builtin_elementwise_fma(splat2(h1.x), w.whh01[4], e01);
    e23 = __builtin_elementwise_fma(splat2(h1.x), w.whh23[4], e23);
    o01 = __builtin_elementwise_fma(splat2(h1.w), w.whh01[7], o01);
    o23 = __builtin_elementwise_fma(splat2(h1.w), w.whh23[7], o23);
    e01 = __builtin_elementwise_fma(splat2(h1.z), w.whh01[6], e01);
    e23 = __builtin_elementwise_fma(splat2(h1.z), w.whh23[6], e23);
    o01 = __builtin_elementwise_fma(splat2(h2.y), w.whh01[9], o01);
    o23 = __builtin_elementwise_fma(splat2(h2.y), w.whh23[9], o23);
    e01 = __builtin_elementwise_fma(splat2(h2.x), w.whh01[8], e01);
    e23 = __builtin_elementwise_fma(splat2(h2.x), w.whh23[8], e23);
    v2f a01 = e01 + o01;
    v2f a23 = e23 + o23;
    float ig = fast_sigmoid(a01.x);
    float fg = fast_sigmoid(a01.y);
    float gg = fast_tanh(a23.x);
    float og = fast_sigmoid(a23.y);
    c = fmaf(fg, c, ig * gg);
    return og * fast_tanh(c);
}

// One wave per block; 6 elements per wave, one per 10-lane group (lanes 60..63
// ride along on a dummy 7th group slot). Group h lives in LDS at stride 20
// floats so the 6 groups' ds_read_b128 hit disjoint bank quads:
// base banks {0,20,8,28,16,4}. All h exchange is intra-wave (in-order DS),
// so no barriers anywhere.
__global__ __launch_bounds__(64) void bayes_lstm_kernel(
    const float* __restrict__ x,
    const float* __restrict__ w_ih_mu, const float* __restrict__ w_ih_rho,
    const float* __restrict__ w_hh_mu, const float* __restrict__ w_hh_rho,
    const float* __restrict__ b_mu,    const float* __restrict__ b_rho,
    const float* __restrict__ eps_ih,  const float* __restrict__ eps_hh,
    const float* __restrict__ eps_b,
    const float* __restrict__ lin_w,   const float* __restrict__ lin_b,
    float* __restrict__ out, int n_elem)
{
    __shared__ __align__(16) float hbuf[7 * 20];  // 6 real groups + 1 dummy

    const int lane  = threadIdx.x;       // 0..63
    const int g     = lane / 10;         // 0..6 (6 = dummy group, lanes 60..63)
    const int k     = lane - g * 10;     // 0..9 always (unit index)
    const int gbase = g * 10;
    const int b     = blockIdx.x * 6 + g;
    const bool valid = (g < 6) && (b < n_elem);
    const int b_eff = (b < n_elem) ? b : (n_elem - 1);   // clamp for safe loads
    float* hb = hbuf + g * 20;

    // ---- sample weights into registers (k < 10 for every lane) ----
    Wreg w;
    const int c0 = k, c1 = HID + k, c2 = 2 * HID + k, c3 = 3 * HID + k;
    w.wih01 = mk2(samp(w_ih_mu, w_ih_rho, eps_ih, c0), samp(w_ih_mu, w_ih_rho, eps_ih, c1));
    w.wih23 = mk2(samp(w_ih_mu, w_ih_rho, eps_ih, c2), samp(w_ih_mu, w_ih_rho, eps_ih, c3));
    w.b01   = mk2(samp(b_mu, b_rho, eps_b, c0), samp(b_mu, b_rho, eps_b, c1));
    w.b23   = mk2(samp(b_mu, b_rho, eps_b, c2), samp(b_mu, b_rho, eps_b, c3));
#pragma unroll
    for (int j = 0; j < HID; ++j) {
        w.whh01[j] = mk2(samp(w_hh_mu, w_hh_rho, eps_hh, j * 4 * HID + c0),
                         samp(w_hh_mu, w_hh_rho, eps_hh, j * 4 * HID + c1));
        w.whh23[j] = mk2(samp(w_hh_mu, w_hh_rho, eps_hh, j * 4 * HID + c2),
                         samp(w_hh_mu, w_hh_rho, eps_hh, j * 4 * HID + c3));
    }
    const float lw = lin_w[k];

    // zero-init h (+2 pad floats so b128 reads of h[8..11] see zeros)
    hb[k] = 0.f;
    if (k < 2) hb[10 + k] = 0.f;

    float c = 0.f, hk = 0.f;
    const float* xr = x + (size_t)b_eff * T_LEN;
    const bool ldx = (k < 8);
    float xc = ldx ? xr[k] : 0.f;        // chunk 0: lane gbase+k holds x[t=k]
    const float4* p = (const float4*)hb;

    for (int ch = 0; ch < 32; ++ch) {    // 32 chunks x 8 steps = 256
        float xn = 0.f;
        if (ldx && ch < 31) xn = xr[(ch + 1) * 8 + k];   // prefetch next chunk
#pragma unroll
        for (int ti = 0; ti < 8; ++ti) {
            // read h written by previous step (same-wave DS is in-order)
            float4 h0 = p[0], h1 = p[1], h2 = p[2];
            float xt = __shfl(xc, gbase + ti, 64);
            hk = lstm_step(w, xt, h0, h1, h2, c);
            hb[k] = hk;                  // every lane owns a slot: no guard
        }
        xc = xn;
    }

    // ---- linear head: reduce h[k]*lw over the 10-lane group via LDS ----
    hb[k] = hk * lw;                     // pads at 10,11 are still zero
    if (k == 0 && valid) {
        float4 s0 = p[0], s1 = p[1], s2 = p[2];
        out[b] = (s0.x + s0.y + s0.z + s0.w)
               + (s1.x + s1.y + s1.z + s1.w)
               + (s2.x + s2.y + s2.z + s2.w) + lin_b[0];
    }
}

extern "C" void kernel_launch(void* const* d_in, const int* in_sizes, int n_in,
                              void* d_out, int out_size, void* d_ws, size_t ws_size,
                              hipStream_t stream) {
    const float* x        = (const float*)d_in[0];
    const float* w_ih_mu  = (const float*)d_in[1];
    const float* w_ih_rho = (const float*)d_in[2];
    const float* w_hh_mu  = (const float*)d_in[3];
    const float* w_hh_rho = (const float*)d_in[4];
    const float* b_mu     = (const float*)d_in[5];
    const float* b_rho    = (const float*)d_in[6];
    const float* eps_ih   = (const float*)d_in[7];
    const float* eps_hh   = (const float*)d_in[8];
    const float* eps_b    = (const float*)d_in[9];
    const float* lin_w    = (const float*)d_in[10];
    const float* lin_b    = (const float*)d_in[11];
    float* out = (float*)d_out;

    const int n_b = in_sizes[0] / T_LEN;     // 8192
    dim3 grid((n_b + 5) / 6), block(64);     // 1 wave/block, 6 elements/wave
    hipLaunchKernelGGL(bayes_lstm_kernel, grid, block, 0, stream,
                       x, w_ih_mu, w_ih_rho, w_hh_mu, w_hh_rho, b_mu, b_rho,
                       eps_ih, eps_hh, eps_b, lin_w, lin_b, out, n_b);
}